// Round 2
// baseline (48009.647 us; speedup 1.0000x reference)
//
#include <hip/hip_runtime.h>
#include <math.h>

// Problem constants
constexpr int C_B   = 512;
constexpr int C_T   = 365;
constexpr int C_IN  = 10;
constexpr int C_H   = 256;
constexpr int C_OUT = 20;

// Decomposition: 32 groups (16 batch rows each) x 16 blocks (16 hidden units each)
constexpr int N_GROUPS = 32;
constexpr int BT       = 16;   // batch tile per group
constexpr int JS       = 16;   // j-slice per block
constexpr int JBLK     = 16;   // blocks per group
constexpr int NTHREADS = 256;
constexpr int NBLOCKS  = N_GROUPS * JBLK; // 512  -> 2 blocks/CU, 8 waves/CU

// Workspace layout (floats):
// h0[2][512][256] at 0 ; h1[2][512][256] at 262144 ; counters (uint) at 524288
constexpr int WS_H0   = 0;
constexpr int WS_H1   = 2 * C_B * C_H;
constexpr int WS_CTR  = 4 * C_B * C_H;

__device__ __forceinline__ void fma4(float4& a, const float4 w, const float4 h) {
    a.x += w.x * h.x; a.y += w.y * h.y; a.z += w.z * h.z; a.w += w.w * h.w;
}
__device__ __forceinline__ float hsum4(const float4 v) {
    return (v.x + v.y) + (v.z + v.w);
}
__device__ __forceinline__ float sigmoidf_(float v) {
    return 1.0f / (1.0f + expf(-v));
}

// All h-state traffic uses relaxed agent-scope atomics: HW-coherent at L3,
// bypasses the non-coherent L1/L2 -> no cache-invalidating fences needed,
// so weights stay warm in L2/L1 across all 730 barriers.
__device__ __forceinline__ float gload(const float* p) {
    return __hip_atomic_load(p, __ATOMIC_RELAXED, __HIP_MEMORY_SCOPE_AGENT);
}
__device__ __forceinline__ void gstore(float* p, float v) {
    __hip_atomic_store(p, v, __ATOMIC_RELAXED, __HIP_MEMORY_SCOPE_AGENT);
}

// Stage h tile [16][256] (agent-coherent source) into padded LDS [16][260].
// tid = column; fully coalesced 256B/wave-instr, 16 loads in flight.
__device__ __forceinline__ void stage16(const float* __restrict__ src,
                                        float (*lds)[C_H + 4], int tid) {
    float v[BT];
#pragma unroll
    for (int i = 0; i < BT; i++) v[i] = gload(src + i * C_H + tid);
#pragma unroll
    for (int i = 0; i < BT; i++) lds[i][tid] = v[i];
}

// Triple-gate dot product for one batch row: weights from global (L1/L2-warm),
// h row from LDS (16-lane broadcast, conflict-free banks).
__device__ __forceinline__ void pass3(const float* __restrict__ Wr,
                                      const float* __restrict__ Wz,
                                      const float* __restrict__ Wn,
                                      const float* hrow,
                                      float& ar, float& az, float& an) {
    float4 vr = {0,0,0,0}, vz = {0,0,0,0}, vn = {0,0,0,0};
#pragma unroll 4
    for (int k = 0; k < C_H; k += 4) {
        float4 wr = *(const float4*)(Wr + k);
        float4 wz = *(const float4*)(Wz + k);
        float4 wn = *(const float4*)(Wn + k);
        float4 h  = *(const float4*)(hrow + k);
        fma4(vr, wr, h); fma4(vz, wz, h); fma4(vn, wn, h);
    }
    ar += hsum4(vr); az += hsum4(vz); an += hsum4(vn);
}

// Fence-free 16-block group barrier: monotonically increasing relaxed
// agent-scope counter. The compiler-emitted vmcnt(0) before s_barrier drains
// every thread's (write-through) h stores; no buffer_wbl2 / buffer_inv.
__device__ __forceinline__ void group_barrier(unsigned* c, unsigned target) {
    __syncthreads();
    if (threadIdx.x == 0) {
        asm volatile("s_waitcnt vmcnt(0)" ::: "memory");
        __hip_atomic_fetch_add(c, 1u, __ATOMIC_RELAXED, __HIP_MEMORY_SCOPE_AGENT);
        while (__hip_atomic_load(c, __ATOMIC_RELAXED, __HIP_MEMORY_SCOPE_AGENT) < target) {
            __builtin_amdgcn_s_sleep(1);
        }
        asm volatile("" ::: "memory");
    }
    __syncthreads();
}

__global__ void init_ctrs(float* ws) {
    unsigned* c = (unsigned*)(ws + WS_CTR);
    c[threadIdx.x] = 0;
}

__global__ __launch_bounds__(NTHREADS, 2) void gru_persistent(
    const float* __restrict__ x,
    const float* __restrict__ Wih0, const float* __restrict__ Whh0,
    const float* __restrict__ bih0, const float* __restrict__ bhh0,
    const float* __restrict__ Wih1, const float* __restrict__ Whh1,
    const float* __restrict__ bih1, const float* __restrict__ bhh1,
    const float* __restrict__ Wout, const float* __restrict__ bout,
    float* __restrict__ out, float* __restrict__ ws) {

    __shared__ float lds_h[BT][C_H + 4];
    __shared__ float lds_x[BT][C_IN];
    __shared__ float lds_logits[BT * C_OUT];

    const int tid = threadIdx.x;
    const int g   = blockIdx.x >> 4;   // group 0..31
    const int r   = blockIdx.x & 15;   // j-block within group
    const int b0  = g * BT;
    const int j0  = r * JS;
    const int jl  = tid & 15;
    const int bp  = tid >> 4;          // batch row 0..15 (local)
    const int j   = j0 + jl;           // hidden unit 0..255

    float* h0buf[2] = { ws + WS_H0, ws + WS_H0 + C_B * C_H };
    float* h1buf[2] = { ws + WS_H1, ws + WS_H1 + C_B * C_H };
    unsigned* ctr = (unsigned*)(ws + WS_CTR) + g * 32;

    // Per-thread persistent: W_ih0 rows (K=10) and biases for this j.
    float wir[C_IN], wiz[C_IN], win[C_IN];
#pragma unroll
    for (int i = 0; i < C_IN; i++) {
        wir[i] = Wih0[(j)         * C_IN + i];
        wiz[i] = Wih0[(C_H + j)   * C_IN + i];
        win[i] = Wih0[(2*C_H + j) * C_IN + i];
    }
    const float br0  = bih0[j]         + bhh0[j];
    const float bz0  = bih0[C_H + j]   + bhh0[C_H + j];
    const float bin0 = bih0[2*C_H + j];
    const float bhn0 = bhh0[2*C_H + j];
    const float br1  = bih1[j]         + bhh1[j];
    const float bz1  = bih1[C_H + j]   + bhh1[C_H + j];
    const float bin1 = bih1[2*C_H + j];
    const float bhn1 = bhh1[2*C_H + j];

    const float* Wr0 = Whh0 + (j)         * C_H;
    const float* Wz0 = Whh0 + (C_H + j)   * C_H;
    const float* Wn0 = Whh0 + (2*C_H + j) * C_H;
    const float* Air = Wih1 + (j)         * C_H;
    const float* Aiz = Wih1 + (C_H + j)   * C_H;
    const float* Ain = Wih1 + (2*C_H + j) * C_H;
    const float* Ahr = Whh1 + (j)         * C_H;
    const float* Ahz = Whh1 + (C_H + j)   * C_H;
    const float* Ahn = Whh1 + (2*C_H + j) * C_H;

    unsigned target = 0;
    int p = 0;

    for (int t = 0; t < C_T; t++) {
        // ---------------- Phase A: layer 0 ----------------
        if (tid < BT * C_IN) {
            int bb = tid / C_IN, i = tid - bb * C_IN;
            lds_x[bb][i] = x[(b0 + bb) * (C_T * C_IN) + t * C_IN + i];
        }
        if (t > 0) stage16(h0buf[p] + b0 * C_H, lds_h, tid);
        __syncthreads();

        float ar = br0, az = bz0, ain = bin0, ahn = bhn0;
#pragma unroll
        for (int i = 0; i < C_IN; i++) {
            float xv = lds_x[bp][i];
            ar += xv * wir[i]; az += xv * wiz[i]; ain += xv * win[i];
        }
        float hp = 0.0f;
        if (t > 0) {
            hp = lds_h[bp][j];
            pass3(Wr0, Wz0, Wn0, &lds_h[bp][0], ar, az, ahn);
        }
        {
            float rr = sigmoidf_(ar), zz = sigmoidf_(az);
            float nn = tanhf(ain + rr * ahn);
            gstore(h0buf[1 - p] + (b0 + bp) * C_H + j, zz * (hp - nn) + nn);
        }
        target += JBLK;
        group_barrier(ctr, target);

        // ---------------- Phase B: layer 1 ----------------
        stage16(h0buf[1 - p] + b0 * C_H, lds_h, tid);
        __syncthreads();

        float ar1 = br1, az1 = bz1, ain1 = bin1, ahn1 = bhn1;
        pass3(Air, Aiz, Ain, &lds_h[bp][0], ar1, az1, ain1);   // input gates from h0_new
        __syncthreads();

        float h1p = 0.0f;
        if (t > 0) {
            stage16(h1buf[p] + b0 * C_H, lds_h, tid);
            __syncthreads();
            h1p = lds_h[bp][j];
            pass3(Ahr, Ahz, Ahn, &lds_h[bp][0], ar1, az1, ahn1);
        }
        {
            float rr = sigmoidf_(ar1), zz = sigmoidf_(az1);
            float nn = tanhf(ain1 + rr * ahn1);
            gstore(h1buf[1 - p] + (b0 + bp) * C_H + j, zz * (h1p - nn) + nn);
        }
        target += JBLK;
        group_barrier(ctr, target);
        p ^= 1;
    }

    // ---------------- Epilogue: classifier + softmax (block r==0 per group) ----
    if (r == 0) {
        stage16(h1buf[p] + b0 * C_H, lds_h, tid);
        __syncthreads();
        for (int u = tid; u < BT * C_OUT; u += NTHREADS) {
            int bb = u / C_OUT, o = u - bb * C_OUT;
            const float* wrow = Wout + o * C_H;
            float4 v = {0,0,0,0};
#pragma unroll 4
            for (int k = 0; k < C_H; k += 4) {
                float4 w = *(const float4*)(wrow + k);
                float4 h = *(const float4*)(&lds_h[bb][k]);
                fma4(v, w, h);
            }
            lds_logits[bb * C_OUT + o] = bout[o] + hsum4(v);
        }
        __syncthreads();
        if (tid < BT) {
            float mx = -1e30f;
#pragma unroll
            for (int o = 0; o < C_OUT; o++) mx = fmaxf(mx, lds_logits[tid * C_OUT + o]);
            float e[C_OUT];
            float s = 0.0f;
#pragma unroll
            for (int o = 0; o < C_OUT; o++) { e[o] = expf(lds_logits[tid * C_OUT + o] - mx); s += e[o]; }
            float inv = 1.0f / s;
#pragma unroll
            for (int o = 0; o < C_OUT; o++) out[(b0 + tid) * C_OUT + o] = e[o] * inv;
        }
    }
}

extern "C" void kernel_launch(void* const* d_in, const int* in_sizes, int n_in,
                              void* d_out, int out_size, void* d_ws, size_t ws_size,
                              hipStream_t stream) {
    const float* x    = (const float*)d_in[0];
    // d_in[1] = times (unused), d_in[2] = interpolation_method (unused)
    const float* Wih0 = (const float*)d_in[3];
    const float* Whh0 = (const float*)d_in[4];
    const float* bih0 = (const float*)d_in[5];
    const float* bhh0 = (const float*)d_in[6];
    const float* Wih1 = (const float*)d_in[7];
    const float* Whh1 = (const float*)d_in[8];
    const float* bih1 = (const float*)d_in[9];
    const float* bhh1 = (const float*)d_in[10];
    const float* Wout = (const float*)d_in[11];
    const float* bout = (const float*)d_in[12];
    float* out = (float*)d_out;
    float* ws  = (float*)d_ws;

    init_ctrs<<<1, 1024, 0, stream>>>(ws);
    gru_persistent<<<NBLOCKS, NTHREADS, 0, stream>>>(
        x, Wih0, Whh0, bih0, bhh0, Wih1, Whh1, bih1, bhh1, Wout, bout, out, ws);
}

// Round 3
// 16563.487 us; speedup vs baseline: 2.8985x; 2.8985x over previous
//
#include <hip/hip_runtime.h>
#include <math.h>

// Problem constants
constexpr int C_B   = 512;
constexpr int C_T   = 365;
constexpr int C_IN  = 10;
constexpr int C_H   = 256;
constexpr int C_OUT = 20;

// Grid split per step-kernel: blocks 0..63 = layer0 (8 batch rows each),
// blocks 64..191 = layer1 (4 batch rows each). No cross-block deps inside
// a launch; layer1 runs one timestep behind layer0 (software pipeline across
// kernel boundaries; dispatch boundary = the only sync primitive used).
constexpr int L0_BLOCKS = 64;
constexpr int L0_ROWS   = 8;
constexpr int L1_BLOCKS = 128;
constexpr int L1_ROWS   = 4;
constexpr int NB        = L0_BLOCKS + L1_BLOCKS;   // 192

__device__ __forceinline__ float fsig(float v)  { return 1.0f / (1.0f + __expf(-v)); }
__device__ __forceinline__ float ftanh(float v) { return 2.0f / (1.0f + __expf(-2.0f * v)) - 1.0f; }

__global__ __launch_bounds__(256) void gru_step(
    const float* __restrict__ x, int t,
    const float* __restrict__ h0_src, float* __restrict__ h0_dst,
    const float* __restrict__ h1_src, float* __restrict__ h1_dst,
    const float* __restrict__ Wih0, const float* __restrict__ Whh0,
    const float* __restrict__ bih0, const float* __restrict__ bhh0,
    const float* __restrict__ Wih1, const float* __restrict__ Whh1,
    const float* __restrict__ bih1, const float* __restrict__ bhh1,
    int do_l0, int l0_zero, int do_l1, int l1_zero)
{
    const int tid = threadIdx.x;
    const int j   = tid;                     // hidden unit 0..255

    if (blockIdx.x < L0_BLOCKS) {
        // ---------------- layer 0, step t ----------------
        if (!do_l0) return;
        __shared__ float hs[L0_ROWS][C_H + 4];
        __shared__ float xs[L0_ROWS][C_IN];
        const int b0 = blockIdx.x * L0_ROWS;

        if (tid < L0_ROWS * C_IN) {
            int r = tid / C_IN, c = tid - r * C_IN;
            xs[r][c] = x[(b0 + r) * (C_T * C_IN) + t * C_IN + c];
        }
        if (!l0_zero) {
#pragma unroll
            for (int i = 0; i < L0_ROWS; i++) hs[i][tid] = h0_src[(b0 + i) * C_H + tid];
        }
        __syncthreads();

        float ar[L0_ROWS], az[L0_ROWS], ain[L0_ROWS], ahn[L0_ROWS];
        const float br = bih0[j] + bhh0[j];
        const float bz = bih0[C_H + j] + bhh0[C_H + j];
        const float bi = bih0[2 * C_H + j];
        const float bh = bhh0[2 * C_H + j];
#pragma unroll
        for (int r = 0; r < L0_ROWS; r++) { ar[r] = br; az[r] = bz; ain[r] = bi; ahn[r] = bh; }

        // x-part (K=10)
#pragma unroll
        for (int i = 0; i < C_IN; i++) {
            float wr = Wih0[j * C_IN + i];
            float wz = Wih0[(C_H + j) * C_IN + i];
            float wn = Wih0[(2 * C_H + j) * C_IN + i];
#pragma unroll
            for (int r = 0; r < L0_ROWS; r++) {
                float xv = xs[r][i];
                ar[r] += xv * wr; az[r] += xv * wz; ain[r] += xv * wn;
            }
        }
        // h-part (K=256)
        if (!l0_zero) {
            const float* Wr = Whh0 + j * C_H;
            const float* Wz = Whh0 + (C_H + j) * C_H;
            const float* Wn = Whh0 + (2 * C_H + j) * C_H;
#pragma unroll 2
            for (int k = 0; k < C_H; k += 4) {
                float4 wr = *(const float4*)(Wr + k);
                float4 wz = *(const float4*)(Wz + k);
                float4 wn = *(const float4*)(Wn + k);
#pragma unroll
                for (int r = 0; r < L0_ROWS; r++) {
                    float4 h = *(const float4*)(&hs[r][k]);
                    ar[r]  += wr.x*h.x + wr.y*h.y + wr.z*h.z + wr.w*h.w;
                    az[r]  += wz.x*h.x + wz.y*h.y + wz.z*h.z + wz.w*h.w;
                    ahn[r] += wn.x*h.x + wn.y*h.y + wn.z*h.z + wn.w*h.w;
                }
            }
        }
#pragma unroll
        for (int r = 0; r < L0_ROWS; r++) {
            float hp = l0_zero ? 0.0f : hs[r][j];
            float rr = fsig(ar[r]), zz = fsig(az[r]);
            float nn = ftanh(ain[r] + rr * ahn[r]);
            h0_dst[(b0 + r) * C_H + j] = zz * (hp - nn) + nn;
        }
    } else {
        // ---------------- layer 1, step t-1 ----------------
        if (!do_l1) return;
        __shared__ float as_[L1_ROWS][C_H + 4];   // layer-0 output (this step's input)
        __shared__ float bs[L1_ROWS][C_H + 4];    // layer-1 previous hidden
        const int b0 = (blockIdx.x - L0_BLOCKS) * L1_ROWS;

#pragma unroll
        for (int i = 0; i < L1_ROWS; i++) as_[i][tid] = h0_src[(b0 + i) * C_H + tid];
        if (!l1_zero) {
#pragma unroll
            for (int i = 0; i < L1_ROWS; i++) bs[i][tid] = h1_src[(b0 + i) * C_H + tid];
        }
        __syncthreads();

        float ar[L1_ROWS], az[L1_ROWS], ain[L1_ROWS], ahn[L1_ROWS];
        const float br = bih1[j] + bhh1[j];
        const float bz = bih1[C_H + j] + bhh1[C_H + j];
        const float bi = bih1[2 * C_H + j];
        const float bh = bhh1[2 * C_H + j];
#pragma unroll
        for (int r = 0; r < L1_ROWS; r++) { ar[r] = br; az[r] = bz; ain[r] = bi; ahn[r] = bh; }

        // input-gate pass over layer0 output (K=256)
        {
            const float* Ar = Wih1 + j * C_H;
            const float* Az = Wih1 + (C_H + j) * C_H;
            const float* An = Wih1 + (2 * C_H + j) * C_H;
#pragma unroll 2
            for (int k = 0; k < C_H; k += 4) {
                float4 wr = *(const float4*)(Ar + k);
                float4 wz = *(const float4*)(Az + k);
                float4 wn = *(const float4*)(An + k);
#pragma unroll
                for (int r = 0; r < L1_ROWS; r++) {
                    float4 h = *(const float4*)(&as_[r][k]);
                    ar[r]  += wr.x*h.x + wr.y*h.y + wr.z*h.z + wr.w*h.w;
                    az[r]  += wz.x*h.x + wz.y*h.y + wz.z*h.z + wz.w*h.w;
                    ain[r] += wn.x*h.x + wn.y*h.y + wn.z*h.z + wn.w*h.w;
                }
            }
        }
        // hidden-gate pass over h1 prev (K=256)
        if (!l1_zero) {
            const float* Hr = Whh1 + j * C_H;
            const float* Hz = Whh1 + (C_H + j) * C_H;
            const float* Hn = Whh1 + (2 * C_H + j) * C_H;
#pragma unroll 2
            for (int k = 0; k < C_H; k += 4) {
                float4 wr = *(const float4*)(Hr + k);
                float4 wz = *(const float4*)(Hz + k);
                float4 wn = *(const float4*)(Hn + k);
#pragma unroll
                for (int r = 0; r < L1_ROWS; r++) {
                    float4 h = *(const float4*)(&bs[r][k]);
                    ar[r]  += wr.x*h.x + wr.y*h.y + wr.z*h.z + wr.w*h.w;
                    az[r]  += wz.x*h.x + wz.y*h.y + wz.z*h.z + wz.w*h.w;
                    ahn[r] += wn.x*h.x + wn.y*h.y + wn.z*h.z + wn.w*h.w;
                }
            }
        }
#pragma unroll
        for (int r = 0; r < L1_ROWS; r++) {
            float hp = l1_zero ? 0.0f : bs[r][j];
            float rr = fsig(ar[r]), zz = fsig(az[r]);
            float nn = ftanh(ain[r] + rr * ahn[r]);
            h1_dst[(b0 + r) * C_H + j] = zz * (hp - nn) + nn;
        }
    }
}

__global__ __launch_bounds__(256) void classifier_kernel(
    const float* __restrict__ h1,
    const float* __restrict__ Wout, const float* __restrict__ bout,
    float* __restrict__ out)
{
    __shared__ float hs[32][C_H + 4];
    __shared__ float lg[32 * C_OUT];
    const int tid = threadIdx.x;
    const int b0  = blockIdx.x * 32;
#pragma unroll
    for (int i = 0; i < 32; i++) hs[i][tid] = h1[(b0 + i) * C_H + tid];
    __syncthreads();
    for (int u = tid; u < 32 * C_OUT; u += 256) {
        int bb = u / C_OUT, o = u - bb * C_OUT;
        const float* wr = Wout + o * C_H;
        float acc = bout[o];
#pragma unroll 4
        for (int k = 0; k < C_H; k += 4) {
            float4 w = *(const float4*)(wr + k);
            float4 h = *(const float4*)(&hs[bb][k]);
            acc += w.x*h.x + w.y*h.y + w.z*h.z + w.w*h.w;
        }
        lg[u] = acc;
    }
    __syncthreads();
    if (tid < 32) {
        float mx = -1e30f;
#pragma unroll
        for (int o = 0; o < C_OUT; o++) mx = fmaxf(mx, lg[tid * C_OUT + o]);
        float e[C_OUT];
        float s = 0.0f;
#pragma unroll
        for (int o = 0; o < C_OUT; o++) { e[o] = __expf(lg[tid * C_OUT + o] - mx); s += e[o]; }
        float inv = 1.0f / s;
#pragma unroll
        for (int o = 0; o < C_OUT; o++) out[(b0 + tid) * C_OUT + o] = e[o] * inv;
    }
}

extern "C" void kernel_launch(void* const* d_in, const int* in_sizes, int n_in,
                              void* d_out, int out_size, void* d_ws, size_t ws_size,
                              hipStream_t stream) {
    const float* x    = (const float*)d_in[0];
    // d_in[1] = times (unused), d_in[2] = interpolation_method (unused)
    const float* Wih0 = (const float*)d_in[3];
    const float* Whh0 = (const float*)d_in[4];
    const float* bih0 = (const float*)d_in[5];
    const float* bhh0 = (const float*)d_in[6];
    const float* Wih1 = (const float*)d_in[7];
    const float* Whh1 = (const float*)d_in[8];
    const float* bih1 = (const float*)d_in[9];
    const float* bhh1 = (const float*)d_in[10];
    const float* Wout = (const float*)d_in[11];
    const float* bout = (const float*)d_in[12];
    float* out  = (float*)d_out;
    float* ws_f = (float*)d_ws;

    float* h0A = ws_f;
    float* h0B = ws_f + C_B * C_H;
    float* h1A = ws_f + 2 * C_B * C_H;
    float* h1B = ws_f + 3 * C_B * C_H;

    // Launch k: layer0 computes h0_k; layer1 computes h1_{k-1} (pipelined).
    // Launch C_T (k=365): layer1-only computes h1_{364}. Then classifier.
    for (int k = 0; k <= C_T; k++) {
        const float* h0s = (k & 1) ? h0A : h0B;   // holds h0_{k-1}
        float*       h0d = (k & 1) ? h0B : h0A;   // receives h0_k
        const float* h1s = (k & 1) ? h1B : h1A;   // holds h1_{k-2}
        float*       h1d = (k & 1) ? h1A : h1B;   // receives h1_{k-1}
        int do_l0 = (k < C_T) ? 1 : 0;
        int l0z   = (k == 0) ? 1 : 0;
        int do_l1 = (k >= 1) ? 1 : 0;
        int l1z   = (k == 1) ? 1 : 0;
        gru_step<<<NB, 256, 0, stream>>>(x, k, h0s, h0d, h1s, h1d,
                                         Wih0, Whh0, bih0, bhh0,
                                         Wih1, Whh1, bih1, bhh1,
                                         do_l0, l0z, do_l1, l1z);
    }
    // final h1 written at k=365 (odd) -> h1A
    classifier_kernel<<<C_B / 32, 256, 0, stream>>>(h1A, Wout, bout, out);
}

// Round 4
// 6073.465 us; speedup vs baseline: 7.9048x; 2.7272x over previous
//
#include <hip/hip_runtime.h>
#include <math.h>

// Problem constants
constexpr int C_B   = 512;
constexpr int C_T   = 365;
constexpr int C_IN  = 10;
constexpr int C_H   = 256;
constexpr int C_OUT = 20;

// Step-kernel geometry:
//   L0 blocks: 128  = 2 j-halves(128j) x 64 row-tiles(8 rows). 256 thr = 4 waves:
//              wave = (jthalf, khalf). Each thread: 8 rows x 1 j x 4 gate-accs.
//   L1 blocks: 256  = 4 j-tiles(64j) x 64 row-tiles(8 rows). 4 waves = (mat, khalf).
// Weights pre-packed [k][j][3] (12B/lane, coalesced). h rows staged in LDS,
// read as uniform-address float4 broadcasts. Partials reduced via padded LDS.
constexpr int L0_BLOCKS = 128;
constexpr int L1_BLOCKS = 256;
constexpr int NB        = L0_BLOCKS + L1_BLOCKS;   // 384
constexpr int ROWS      = 8;

// Workspace layout (float offsets)
constexpr int WS_P0  = 0;                 // packed Whh0 [256][256][3]
constexpr int WS_P1i = 196608;            // packed Wih1
constexpr int WS_P1h = 393216;            // packed Whh1
constexpr int WS_PX  = 589824;            // packed Wih0 [10][256][3]
constexpr int WS_H   = 597504;            // 4 x 131072 h buffers

struct f3 { float x, y, z; };

__device__ __forceinline__ float fsig(float v)  { return 1.0f / (1.0f + __expf(-v)); }
__device__ __forceinline__ float ftanh(float v) { return 2.0f / (1.0f + __expf(-2.0f * v)) - 1.0f; }

__global__ void prep_weights(const float* __restrict__ Wih0,
                             const float* __restrict__ Whh0,
                             const float* __restrict__ Wih1,
                             const float* __restrict__ Whh1,
                             float* __restrict__ ws) {
    const int bi = blockIdx.x;
    const int j  = threadIdx.x;
    if (bi < 768) {
        const int mat = bi >> 8;          // 0: Whh0, 1: Wih1, 2: Whh1
        const int k   = bi & 255;
        const float* S = (mat == 0) ? Whh0 : (mat == 1) ? Wih1 : Whh1;
        float* D = ws + (mat == 0 ? WS_P0 : (mat == 1) ? WS_P1i : WS_P1h);
#pragma unroll
        for (int g = 0; g < 3; g++)
            D[(k * 256 + j) * 3 + g] = S[(g * 256 + j) * 256 + k];
    } else {
        float* D = ws + WS_PX;
#pragma unroll
        for (int i = 0; i < C_IN; i++)
#pragma unroll
            for (int g = 0; g < 3; g++)
                D[(i * 256 + j) * 3 + g] = Wih0[(g * 256 + j) * C_IN + i];
    }
}

__global__ __launch_bounds__(256) void gru_step(
    const float* __restrict__ x, int t,
    const float* __restrict__ h0_src, float* __restrict__ h0_dst,
    const float* __restrict__ h1_src, float* __restrict__ h1_dst,
    const float* __restrict__ bih0, const float* __restrict__ bhh0,
    const float* __restrict__ bih1, const float* __restrict__ bhh1,
    const float* __restrict__ ws,
    int do_l0, int l0_zero, int do_l1, int l1_zero)
{
    __shared__ float hA[ROWS][260];
    __shared__ float hB[ROWS][260];
    __shared__ float xls[ROWS][10];
    __shared__ float ex[4][ROWS][64][5];

    const int tid  = threadIdx.x;
    const int lane = tid & 63;
    const int w    = tid >> 6;     // wave 0..3

    if (blockIdx.x < L0_BLOCKS) {
        // ======================= layer 0, step t =======================
        if (!do_l0) return;
        const int bt = blockIdx.x & 63;
        const int jt = blockIdx.x >> 6;        // 0..1 (128-j half)
        const int b0 = bt * ROWS;
        const int jthalf = w >> 1;             // which 64-j slice of this 128
        const int kh     = w & 1;
        const int jg     = jt * 128 + jthalf * 64 + lane;   // global j

        // stage h0_prev tile [8][256] and x tile [8][10]
        if (!l0_zero) {
#pragma unroll
            for (int q = 0; q < 8; q++) {
                int idx = q * 256 + tid;
                int r = idx >> 8, k = idx & 255;
                hA[r][k] = h0_src[(b0 + r) * C_H + k];
            }
        }
        if (tid < ROWS * C_IN) {
            int r = tid / C_IN, i = tid - r * C_IN;
            xls[r][i] = x[(b0 + r) * (C_T * C_IN) + t * C_IN + i];
        }
        __syncthreads();

        float pr[ROWS], pz[ROWS], pin[ROWS], phn[ROWS];
#pragma unroll
        for (int r = 0; r < ROWS; r++) { pr[r] = 0; pz[r] = 0; pin[r] = 0; phn[r] = 0; }

        // x-part: 5 i's per k-half wave
        {
            const f3* PX = (const f3*)(ws + WS_PX);
            const int i0 = kh * 5;
#pragma unroll
            for (int ii = 0; ii < 5; ii++) {
                const int i = i0 + ii;
                f3 wx = PX[i * 256 + jg];
#pragma unroll
                for (int r = 0; r < ROWS; r++) {
                    float xv = xls[r][i];
                    pr[r] += wx.x * xv; pz[r] += wx.y * xv; pin[r] += wx.z * xv;
                }
            }
        }
        // h-part: 128 k's per wave
        if (!l0_zero) {
            const f3* P0 = (const f3*)(ws + WS_P0);
            const int k0 = kh * 128;
            for (int k4 = k0; k4 < k0 + 128; k4 += 4) {
                float4 hv[ROWS];
#pragma unroll
                for (int r = 0; r < ROWS; r++) hv[r] = *(const float4*)&hA[r][k4];
#pragma unroll
                for (int kk = 0; kk < 4; kk++) {
                    f3 wv = P0[(k4 + kk) * 256 + jg];
#pragma unroll
                    for (int r = 0; r < ROWS; r++) {
                        float hc = (kk == 0) ? hv[r].x : (kk == 1) ? hv[r].y : (kk == 2) ? hv[r].z : hv[r].w;
                        pr[r] += wv.x * hc; pz[r] += wv.y * hc; phn[r] += wv.z * hc;
                    }
                }
            }
        }
        // write partials
#pragma unroll
        for (int r = 0; r < ROWS; r++) {
            ex[w][r][lane][0] = pr[r];
            ex[w][r][lane][1] = pz[r];
            ex[w][r][lane][2] = pin[r];
            ex[w][r][lane][3] = phn[r];
        }
        __syncthreads();

        // combine: 8 rows x 128 j = 1024 outputs, 4 per thread
#pragma unroll
        for (int q = 0; q < 4; q++) {
            int p   = tid + 256 * q;
            int jl  = p & 127;
            int row = p >> 7;
            int jh  = jl >> 6;
            int jn  = jl & 63;
            int w0  = jh * 2;
            int jo  = jt * 128 + jl;
            float ar  = ex[w0][row][jn][0] + ex[w0 + 1][row][jn][0] + bih0[jo] + bhh0[jo];
            float az  = ex[w0][row][jn][1] + ex[w0 + 1][row][jn][1] + bih0[256 + jo] + bhh0[256 + jo];
            float ain = ex[w0][row][jn][2] + ex[w0 + 1][row][jn][2] + bih0[512 + jo];
            float ahn = ex[w0][row][jn][3] + ex[w0 + 1][row][jn][3] + bhh0[512 + jo];
            float hp  = l0_zero ? 0.0f : h0_src[(b0 + row) * C_H + jo];
            float rr = fsig(ar), zz = fsig(az);
            float nn = ftanh(ain + rr * ahn);
            h0_dst[(b0 + row) * C_H + jo] = zz * (hp - nn) + nn;
        }
    } else {
        // ======================= layer 1, step t-1 =======================
        if (!do_l1) return;
        const int bi2 = blockIdx.x - L0_BLOCKS;
        const int bt  = bi2 & 63;
        const int jt  = bi2 >> 6;              // 0..3 (64-j tile)
        const int b0  = bt * ROWS;
        const int mat = w >> 1;                // 0: Wih1 over h0new, 1: Whh1 over h1prev
        const int kh  = w & 1;
        const int jg  = jt * 64 + lane;

        // stage h0new tile (always) and h1prev tile (if t>0)
#pragma unroll
        for (int q = 0; q < 8; q++) {
            int idx = q * 256 + tid;
            int r = idx >> 8, k = idx & 255;
            hA[r][k] = h0_src[(b0 + r) * C_H + k];
        }
        if (!l1_zero) {
#pragma unroll
            for (int q = 0; q < 8; q++) {
                int idx = q * 256 + tid;
                int r = idx >> 8, k = idx & 255;
                hB[r][k] = h1_src[(b0 + r) * C_H + k];
            }
        }
        __syncthreads();

        float pr[ROWS], pz[ROWS], pn[ROWS];
#pragma unroll
        for (int r = 0; r < ROWS; r++) { pr[r] = 0; pz[r] = 0; pn[r] = 0; }

        const bool active = (mat == 0) || !l1_zero;
        if (active) {
            const f3* P = (const f3*)(ws + (mat == 0 ? WS_P1i : WS_P1h));
            const float (*hT)[260] = (mat == 0) ? hA : hB;
            const int k0 = kh * 128;
            for (int k4 = k0; k4 < k0 + 128; k4 += 4) {
                float4 hv[ROWS];
#pragma unroll
                for (int r = 0; r < ROWS; r++) hv[r] = *(const float4*)&hT[r][k4];
#pragma unroll
                for (int kk = 0; kk < 4; kk++) {
                    f3 wv = P[(k4 + kk) * 256 + jg];
#pragma unroll
                    for (int r = 0; r < ROWS; r++) {
                        float hc = (kk == 0) ? hv[r].x : (kk == 1) ? hv[r].y : (kk == 2) ? hv[r].z : hv[r].w;
                        pr[r] += wv.x * hc; pz[r] += wv.y * hc; pn[r] += wv.z * hc;
                    }
                }
            }
        }
#pragma unroll
        for (int r = 0; r < ROWS; r++) {
            ex[w][r][lane][0] = pr[r];
            ex[w][r][lane][1] = pz[r];
            ex[w][r][lane][2] = pn[r];
        }
        __syncthreads();

        // combine: 8 rows x 64 j = 512 outputs, 2 per thread
#pragma unroll
        for (int q = 0; q < 2; q++) {
            int p   = tid + 256 * q;
            int jl  = p & 63;
            int row = p >> 6;
            int jo  = jt * 64 + jl;
            float ar  = ex[0][row][jl][0] + ex[1][row][jl][0] + ex[2][row][jl][0] + ex[3][row][jl][0]
                      + bih1[jo] + bhh1[jo];
            float az  = ex[0][row][jl][1] + ex[1][row][jl][1] + ex[2][row][jl][1] + ex[3][row][jl][1]
                      + bih1[256 + jo] + bhh1[256 + jo];
            float ain = ex[0][row][jl][2] + ex[1][row][jl][2] + bih1[512 + jo];
            float ahn = ex[2][row][jl][2] + ex[3][row][jl][2] + bhh1[512 + jo];
            float hp  = l1_zero ? 0.0f : h1_src[(b0 + row) * C_H + jo];
            float rr = fsig(ar), zz = fsig(az);
            float nn = ftanh(ain + rr * ahn);
            h1_dst[(b0 + row) * C_H + jo] = zz * (hp - nn) + nn;
        }
    }
}

__global__ __launch_bounds__(256) void classifier_kernel(
    const float* __restrict__ h1,
    const float* __restrict__ Wout, const float* __restrict__ bout,
    float* __restrict__ out)
{
    __shared__ float hs[32][C_H + 4];
    __shared__ float lg[32 * C_OUT];
    const int tid = threadIdx.x;
    const int b0  = blockIdx.x * 32;
#pragma unroll
    for (int i = 0; i < 32; i++) hs[i][tid] = h1[(b0 + i) * C_H + tid];
    __syncthreads();
    for (int u = tid; u < 32 * C_OUT; u += 256) {
        int bb = u / C_OUT, o = u - bb * C_OUT;
        const float* wr = Wout + o * C_H;
        float acc = bout[o];
#pragma unroll 4
        for (int k = 0; k < C_H; k += 4) {
            float4 w = *(const float4*)(wr + k);
            float4 h = *(const float4*)(&hs[bb][k]);
            acc += w.x*h.x + w.y*h.y + w.z*h.z + w.w*h.w;
        }
        lg[u] = acc;
    }
    __syncthreads();
    if (tid < 32) {
        float mx = -1e30f;
#pragma unroll
        for (int o = 0; o < C_OUT; o++) mx = fmaxf(mx, lg[tid * C_OUT + o]);
        float e[C_OUT];
        float s = 0.0f;
#pragma unroll
        for (int o = 0; o < C_OUT; o++) { e[o] = __expf(lg[tid * C_OUT + o] - mx); s += e[o]; }
        float inv = 1.0f / s;
#pragma unroll
        for (int o = 0; o < C_OUT; o++) out[(b0 + tid) * C_OUT + o] = e[o] * inv;
    }
}

extern "C" void kernel_launch(void* const* d_in, const int* in_sizes, int n_in,
                              void* d_out, int out_size, void* d_ws, size_t ws_size,
                              hipStream_t stream) {
    const float* x    = (const float*)d_in[0];
    // d_in[1] = times (unused), d_in[2] = interpolation_method (unused)
    const float* Wih0 = (const float*)d_in[3];
    const float* Whh0 = (const float*)d_in[4];
    const float* bih0 = (const float*)d_in[5];
    const float* bhh0 = (const float*)d_in[6];
    const float* Wih1 = (const float*)d_in[7];
    const float* Whh1 = (const float*)d_in[8];
    const float* bih1 = (const float*)d_in[9];
    const float* bhh1 = (const float*)d_in[10];
    const float* Wout = (const float*)d_in[11];
    const float* bout = (const float*)d_in[12];
    float* out  = (float*)d_out;
    float* ws_f = (float*)d_ws;

    prep_weights<<<769, 256, 0, stream>>>(Wih0, Whh0, Wih1, Whh1, ws_f);

    float* h0A = ws_f + WS_H;
    float* h0B = h0A + C_B * C_H;
    float* h1A = h0B + C_B * C_H;
    float* h1B = h1A + C_B * C_H;

    // Launch k: layer0 computes h0_k; layer1 computes h1_{k-1} (pipelined).
    for (int k = 0; k <= C_T; k++) {
        const float* h0s = (k & 1) ? h0A : h0B;   // holds h0_{k-1}
        float*       h0d = (k & 1) ? h0B : h0A;   // receives h0_k
        const float* h1s = (k & 1) ? h1B : h1A;   // holds h1_{k-2}
        float*       h1d = (k & 1) ? h1A : h1B;   // receives h1_{k-1}
        int do_l0 = (k < C_T) ? 1 : 0;
        int l0z   = (k == 0) ? 1 : 0;
        int do_l1 = (k >= 1) ? 1 : 0;
        int l1z   = (k == 1) ? 1 : 0;
        gru_step<<<NB, 256, 0, stream>>>(x, k, h0s, h0d, h1s, h1d,
                                         bih0, bhh0, bih1, bhh1, ws_f,
                                         do_l0, l0z, do_l1, l1z);
    }
    // final h1 written at k=365 (odd) -> h1A
    classifier_kernel<<<C_B / 32, 256, 0, stream>>>(h1A, Wout, bout, out);
}

// Round 5
// 4147.554 us; speedup vs baseline: 11.5754x; 1.4643x over previous
//
#include <hip/hip_runtime.h>
#include <math.h>

typedef __attribute__((ext_vector_type(8))) short short8;
typedef __attribute__((ext_vector_type(4))) float floatx4;

// Problem constants
constexpr int C_B   = 512;
constexpr int C_T   = 365;
constexpr int C_IN  = 10;
constexpr int C_H   = 256;
constexpr int C_OUT = 20;

// Step grid: 128 L0 blocks (32 M-tiles x 4 N-groups of 12 tiles) +
//            256 L1 blocks (32 M-tiles x 8 N-groups of 6 tiles, wave=(mat,jb)).
// Every wave: 3 N-tiles x 8 ksteps x 3 split-passes = 72 MFMA. Uniform load.
constexpr int L0B = 128;
constexpr int L1B = 256;
constexpr int NB  = L0B + L1B;   // 384

// Workspace: packed bf16 weights then fp32 h buffers.
// Packed: mat(3:Whh0,Wih1,Whh1) x plane(2:hi,lo) x [48 nt][8 ks][64 lane][8 e] bf16
constexpr size_t PLANE_U = 48ull * 8 * 64 * 8;     // 196608 ushorts per plane
constexpr size_t WS_H_F  = (6 * PLANE_U) / 2;      // float offset 589824

__device__ __forceinline__ float fsig(float v)  { return 1.0f / (1.0f + __expf(-v)); }
__device__ __forceinline__ float ftanh(float v) { return 2.0f / (1.0f + __expf(-2.0f * v)) - 1.0f; }

__device__ __forceinline__ void split1(float x, unsigned short& hi, unsigned short& lo) {
    unsigned u = __float_as_uint(x);
    hi = (unsigned short)(u >> 16);
    float r = x - __uint_as_float(u & 0xffff0000u);
    lo = (unsigned short)(__float_as_uint(r) >> 16);
}

// Pack one 16-j slice of one gate of one matrix into B-fragment-linear hi/lo planes.
// Tile numbering nt = jb*3 + g  (gate-interleaved so a wave's 3 tiles = r,z,n of one jb).
__global__ __launch_bounds__(256) void prep_pack(const float* __restrict__ Whh0,
                                                 const float* __restrict__ Wih1,
                                                 const float* __restrict__ Whh1,
                                                 unsigned short* __restrict__ PW) {
    const int blk = blockIdx.x;            // 144 = mat(3) x g(3) x jb(16)
    const int mat = blk / 48;
    const int rem = blk % 48;
    const int g   = rem / 16;
    const int jb  = rem % 16;
    const float* S = (mat == 0) ? Whh0 : (mat == 1) ? Wih1 : Whh1;

    const int tid = threadIdx.x;
    const int jl  = tid >> 4;              // 0..15 row within slice
    const int kc  = tid & 15;              // 16-k chunk
    const int j   = jb * 16 + jl;
    const int nt  = jb * 3 + g;

    const float* src = S + (g * 256 + j) * 256 + kc * 16;
    float f[16];
#pragma unroll
    for (int q = 0; q < 4; q++) {
        float4 v = *(const float4*)(src + q * 4);
        f[q * 4 + 0] = v.x; f[q * 4 + 1] = v.y; f[q * 4 + 2] = v.z; f[q * 4 + 3] = v.w;
    }
    unsigned short hi[16], lo[16];
#pragma unroll
    for (int e = 0; e < 16; e++) split1(f[e], hi[e], lo[e]);

    unsigned short* dhi = PW + (size_t)(mat * 2 + 0) * PLANE_U;
    unsigned short* dlo = PW + (size_t)(mat * 2 + 1) * PLANE_U;
    const int ks = kc >> 1;
#pragma unroll
    for (int hh = 0; hh < 2; hh++) {
        const int quad = (kc & 1) * 2 + hh;
        const int L    = quad * 16 + jl;
        const size_t base = ((size_t)(nt * 8 + ks)) * 512 + L * 8;
        short8 vh, vl;
#pragma unroll
        for (int e = 0; e < 8; e++) { vh[e] = (short)hi[hh * 8 + e]; vl[e] = (short)lo[hh * 8 + e]; }
        *(short8*)(dhi + base) = vh;
        *(short8*)(dlo + base) = vl;
    }
}

// Build A hi/lo fragments for this wave's 16-row M-tile directly from fp32 h.
__device__ __forceinline__ void stageA(const float* __restrict__ hsrc, int b0, int lane,
                                       short8* Ahi, short8* Alo) {
    const int m = lane & 15, quad = lane >> 4;
    const float* row = hsrc + (b0 + m) * C_H + quad * 8;
#pragma unroll
    for (int ks = 0; ks < 8; ks++) {
        float4 f0 = *(const float4*)(row + ks * 32);
        float4 f1 = *(const float4*)(row + ks * 32 + 4);
        float f[8] = { f0.x, f0.y, f0.z, f0.w, f1.x, f1.y, f1.z, f1.w };
#pragma unroll
        for (int e = 0; e < 8; e++) {
            unsigned short h, l;
            split1(f[e], h, l);
            Ahi[ks][e] = (short)h; Alo[ks][e] = (short)l;
        }
    }
}

// One N-tile, full K=256, 3-pass split-bf16: acc += A * B^T (fp32-equivalent).
__device__ __forceinline__ void gemm3(const unsigned short* __restrict__ ph,
                                      const unsigned short* __restrict__ pl,
                                      int nt, int lane,
                                      const short8* Ahi, const short8* Alo, floatx4& acc) {
    const unsigned short* bh0 = ph + (size_t)nt * 4096 + lane * 8;
    const unsigned short* bl0 = pl + (size_t)nt * 4096 + lane * 8;
#pragma unroll
    for (int ks = 0; ks < 8; ks++) {
        short8 bh = *(const short8*)(bh0 + ks * 512);
        short8 bl = *(const short8*)(bl0 + ks * 512);
        acc = __builtin_amdgcn_mfma_f32_16x16x32_bf16(Ahi[ks], bh, acc, 0, 0, 0);
        acc = __builtin_amdgcn_mfma_f32_16x16x32_bf16(Alo[ks], bh, acc, 0, 0, 0);
        acc = __builtin_amdgcn_mfma_f32_16x16x32_bf16(Ahi[ks], bl, acc, 0, 0, 0);
    }
}

__global__ __launch_bounds__(256) void gru_step(
    const float* __restrict__ x, int t,
    const float* __restrict__ h0_src, float* __restrict__ h0_dst,
    const float* __restrict__ h1_src, float* __restrict__ h1_dst,
    const float* __restrict__ Wih0,
    const float* __restrict__ bih0, const float* __restrict__ bhh0,
    const float* __restrict__ bih1, const float* __restrict__ bhh1,
    const unsigned short* __restrict__ PW,
    int do_l0, int l0_zero, int do_l1, int l1_zero)
{
    const int tid  = threadIdx.x;
    const int lane = tid & 63;
    const int w    = tid >> 6;
    const int jlo  = lane & 15;
    const int quad = lane >> 4;

    if (blockIdx.x < L0B) {
        // ================= layer 0, step t =================
        if (!do_l0) return;
        __shared__ float xs[16][10];
        const int mt = blockIdx.x >> 2, ng = blockIdx.x & 3;
        const int b0 = mt * 16;
        const int jbg = ng * 4 + w;

        if (tid < 160) {
            int rr = tid / 10, cc = tid - rr * 10;
            xs[rr][cc] = x[(b0 + rr) * (C_T * C_IN) + t * C_IN + cc];
        }

        short8 Ahi[8], Alo[8];
        floatx4 acc[3];
#pragma unroll
        for (int g = 0; g < 3; g++) acc[g] = (floatx4){0.f, 0.f, 0.f, 0.f};

        if (!l0_zero) {
            stageA(h0_src, b0, lane, Ahi, Alo);
            const unsigned short* ph = PW;                 // Whh0 hi
            const unsigned short* pl = PW + PLANE_U;       // Whh0 lo
#pragma unroll
            for (int g = 0; g < 3; g++) gemm3(ph, pl, jbg * 3 + g, lane, Ahi, Alo, acc[g]);
        }
        __syncthreads();

        // -------- combine (wave-local: tiles g=0,1,2 are r,z,n for this jb) --------
        const int j = jbg * 16 + jlo;
        float wxr[10], wxz[10], wxn[10];
#pragma unroll
        for (int i = 0; i < C_IN; i++) {
            wxr[i] = Wih0[j * C_IN + i];
            wxz[i] = Wih0[(256 + j) * C_IN + i];
            wxn[i] = Wih0[(512 + j) * C_IN + i];
        }
        const float b_r = bih0[j] + bhh0[j];
        const float b_z = bih0[256 + j] + bhh0[256 + j];
        const float b_in = bih0[512 + j];
        const float b_hn = bhh0[512 + j];
#pragma unroll
        for (int r = 0; r < 4; r++) {
            const int m = quad * 4 + r;
            float xr = 0.f, xz = 0.f, xn = 0.f;
#pragma unroll
            for (int i = 0; i < C_IN; i++) {
                float xv = xs[m][i];
                xr += xv * wxr[i]; xz += xv * wxz[i]; xn += xv * wxn[i];
            }
            const float hp = l0_zero ? 0.f : h0_src[(b0 + m) * C_H + j];
            const float ar = acc[0][r] + xr + b_r;
            const float az = acc[1][r] + xz + b_z;
            const float inn = xn + b_in;
            const float hn  = acc[2][r] + b_hn;
            const float rg = fsig(ar), zg = fsig(az);
            const float nn = ftanh(inn + rg * hn);
            h0_dst[(b0 + m) * C_H + j] = zg * (hp - nn) + nn;
        }
    } else {
        // ================= layer 1, step t-1 =================
        if (!do_l1) return;
        __shared__ float ldH[2][3][16][17];
        const int blk2 = blockIdx.x - L0B;
        const int mt = blk2 >> 3, ng = blk2 & 7;
        const int b0 = mt * 16;
        const int matid = w >> 1;          // 0: Wih1 over h0new, 1: Whh1 over h1prev
        const int jbsub = w & 1;
        const int jbg = ng * 2 + jbsub;

        short8 Ahi[8], Alo[8];
        floatx4 acc[3];
#pragma unroll
        for (int g = 0; g < 3; g++) acc[g] = (floatx4){0.f, 0.f, 0.f, 0.f};

        const bool active = (matid == 0) || !l1_zero;
        if (active) {
            stageA(matid == 0 ? h0_src : h1_src, b0, lane, Ahi, Alo);
            const unsigned short* ph = PW + (size_t)(matid == 0 ? 2 : 4) * PLANE_U;
            const unsigned short* pl = ph + PLANE_U;
#pragma unroll
            for (int g = 0; g < 3; g++) gemm3(ph, pl, jbg * 3 + g, lane, Ahi, Alo, acc[g]);
        }

        if (matid == 1) {
#pragma unroll
            for (int g = 0; g < 3; g++)
#pragma unroll
                for (int r = 0; r < 4; r++)
                    ldH[jbsub][g][quad * 4 + r][jlo] = acc[g][r];
        }
        __syncthreads();

        if (matid == 0) {
            const int j = jbg * 16 + jlo;
            const float b_r = bih1[j] + bhh1[j];
            const float b_z = bih1[256 + j] + bhh1[256 + j];
            const float b_in = bih1[512 + j];
            const float b_hn = bhh1[512 + j];
#pragma unroll
            for (int r = 0; r < 4; r++) {
                const int m = quad * 4 + r;
                const float hp = l1_zero ? 0.f : h1_src[(b0 + m) * C_H + j];
                const float ar = acc[0][r] + ldH[jbsub][0][m][jlo] + b_r;
                const float az = acc[1][r] + ldH[jbsub][1][m][jlo] + b_z;
                const float inn = acc[2][r] + b_in;
                const float hn  = ldH[jbsub][2][m][jlo] + b_hn;
                const float rg = fsig(ar), zg = fsig(az);
                const float nn = ftanh(inn + rg * hn);
                h1_dst[(b0 + m) * C_H + j] = zg * (hp - nn) + nn;
            }
        }
    }
}

__global__ __launch_bounds__(256) void classifier_kernel(
    const float* __restrict__ h1,
    const float* __restrict__ Wout, const float* __restrict__ bout,
    float* __restrict__ out)
{
    __shared__ float hs[32][C_H + 4];
    __shared__ float lg[32 * C_OUT];
    const int tid = threadIdx.x;
    const int b0  = blockIdx.x * 32;
#pragma unroll
    for (int i = 0; i < 32; i++) hs[i][tid] = h1[(b0 + i) * C_H + tid];
    __syncthreads();
    for (int u = tid; u < 32 * C_OUT; u += 256) {
        int bb = u / C_OUT, o = u - bb * C_OUT;
        const float* wr = Wout + o * C_H;
        float acc = bout[o];
#pragma unroll 4
        for (int k = 0; k < C_H; k += 4) {
            float4 wv = *(const float4*)(wr + k);
            float4 hv = *(const float4*)(&hs[bb][k]);
            acc += wv.x*hv.x + wv.y*hv.y + wv.z*hv.z + wv.w*hv.w;
        }
        lg[u] = acc;
    }
    __syncthreads();
    if (tid < 32) {
        float mx = -1e30f;
#pragma unroll
        for (int o = 0; o < C_OUT; o++) mx = fmaxf(mx, lg[tid * C_OUT + o]);
        float e[C_OUT];
        float s = 0.0f;
#pragma unroll
        for (int o = 0; o < C_OUT; o++) { e[o] = __expf(lg[tid * C_OUT + o] - mx); s += e[o]; }
        float inv = 1.0f / s;
#pragma unroll
        for (int o = 0; o < C_OUT; o++) out[(b0 + tid) * C_OUT + o] = e[o] * inv;
    }
}

extern "C" void kernel_launch(void* const* d_in, const int* in_sizes, int n_in,
                              void* d_out, int out_size, void* d_ws, size_t ws_size,
                              hipStream_t stream) {
    const float* x    = (const float*)d_in[0];
    // d_in[1] = times (unused), d_in[2] = interpolation_method (unused)
    const float* Wih0 = (const float*)d_in[3];
    const float* Whh0 = (const float*)d_in[4];
    const float* bih0 = (const float*)d_in[5];
    const float* bhh0 = (const float*)d_in[6];
    const float* Wih1 = (const float*)d_in[7];
    const float* Whh1 = (const float*)d_in[8];
    const float* bih1 = (const float*)d_in[9];
    const float* bhh1 = (const float*)d_in[10];
    const float* Wout = (const float*)d_in[11];
    const float* bout = (const float*)d_in[12];
    float* out  = (float*)d_out;
    float* ws_f = (float*)d_ws;
    unsigned short* PW = (unsigned short*)d_ws;

    prep_pack<<<144, 256, 0, stream>>>(Whh0, Wih1, Whh1, PW);

    float* h0A = ws_f + WS_H_F;
    float* h0B = h0A + C_B * C_H;
    float* h1A = h0B + C_B * C_H;
    float* h1B = h1A + C_B * C_H;

    // Launch k: layer0 computes h0_k; layer1 computes h1_{k-1} (pipelined).
    for (int k = 0; k <= C_T; k++) {
        const float* h0s = (k & 1) ? h0A : h0B;   // holds h0_{k-1}
        float*       h0d = (k & 1) ? h0B : h0A;   // receives h0_k
        const float* h1s = (k & 1) ? h1B : h1A;   // holds h1_{k-2}
        float*       h1d = (k & 1) ? h1A : h1B;   // receives h1_{k-1}
        int do_l0 = (k < C_T) ? 1 : 0;
        int l0z   = (k == 0) ? 1 : 0;
        int do_l1 = (k >= 1) ? 1 : 0;
        int l1z   = (k == 1) ? 1 : 0;
        gru_step<<<NB, 256, 0, stream>>>(x, k, h0s, h0d, h1s, h1d,
                                         Wih0, bih0, bhh0, bih1, bhh1, PW,
                                         do_l0, l0z, do_l1, l1z);
    }
    // final h1 written at k=365 (odd) -> h1A
    classifier_kernel<<<C_B / 32, 256, 0, stream>>>(h1A, Wout, bout, out);
}

// Round 6
// 3536.163 us; speedup vs baseline: 13.5768x; 1.1729x over previous
//
#include <hip/hip_runtime.h>
#include <math.h>

typedef __attribute__((ext_vector_type(8))) short short8;
typedef __attribute__((ext_vector_type(4))) float floatx4;
typedef unsigned short ushort_t;

// Problem constants
constexpr int C_B   = 512;
constexpr int C_T   = 365;
constexpr int C_IN  = 10;
constexpr int C_H   = 256;
constexpr int C_OUT = 20;

// Step grid: 64 L0 blocks (16 mt x 4 ng) + 128 L1 blocks (16 mt x 8 ng).
// Each block owns 32 batch rows (two 16-row M-tiles sharing B registers).
// Every wave: 3 nt x 8 ks x 3 split-passes x 2 M = 144 MFMA.
constexpr int L0B = 64;
constexpr int L1B = 128;
constexpr int NB  = L0B + L1B;   // 192

// Workspace (ushort units):
// B planes: mat(3: Whh0,Wih1,Whh1) x plane(hi,lo) x [48 nt][8 ks][64 lane][8]
constexpr size_t PLANE_U = 48ull * 8 * 64 * 8;   // 196608
constexpr size_t US_H    = 6 * PLANE_U;          // h planes start
constexpr size_t HP_SZ   = 512 * 256;            // one h plane
// h plane order: 0=h0hi,1=h0lo,2=h1hi,3=h1lo ; each double-buffered [2]

__device__ __forceinline__ ushort_t* hplane(ushort_t* ws, int which, int p) {
    return ws + US_H + (size_t)(which * 2 + p) * HP_SZ;
}

__device__ __forceinline__ float fsig(float v)  { return 1.0f / (1.0f + __expf(-v)); }
__device__ __forceinline__ float ftanh(float v) { return 2.0f / (1.0f + __expf(-2.0f * v)) - 1.0f; }

__device__ __forceinline__ void split1(float x, ushort_t& hi, ushort_t& lo) {
    unsigned u = __float_as_uint(x);
    hi = (ushort_t)(u >> 16);
    float r = x - __uint_as_float(u & 0xffff0000u);
    lo = (ushort_t)(__float_as_uint(r) >> 16);
}

__device__ __forceinline__ void store_h(ushort_t* hp_, ushort_t* lp_, int idx, float v) {
    ushort_t h, l;
    split1(v, h, l);
    hp_[idx] = h; lp_[idx] = l;
}

__device__ __forceinline__ float load_h(const ushort_t* hp_, const ushort_t* lp_, int idx) {
    float a = __uint_as_float(((unsigned)hp_[idx]) << 16);
    float b = __uint_as_float(((unsigned)lp_[idx]) << 16);
    return a + b;
}

// Pack one 16-j slice of one gate of one matrix into B-fragment-linear hi/lo planes.
__global__ __launch_bounds__(256) void prep_pack(const float* __restrict__ Whh0,
                                                 const float* __restrict__ Wih1,
                                                 const float* __restrict__ Whh1,
                                                 ushort_t* __restrict__ PW) {
    const int blk = blockIdx.x;            // 144 = mat(3) x g(3) x jb(16)
    const int mat = blk / 48;
    const int rem = blk % 48;
    const int g   = rem / 16;
    const int jb  = rem % 16;
    const float* S = (mat == 0) ? Whh0 : (mat == 1) ? Wih1 : Whh1;

    const int tid = threadIdx.x;
    const int jl  = tid >> 4;
    const int kc  = tid & 15;
    const int j   = jb * 16 + jl;
    const int nt  = jb * 3 + g;

    const float* src = S + (g * 256 + j) * 256 + kc * 16;
    float f[16];
#pragma unroll
    for (int q = 0; q < 4; q++) {
        float4 v = *(const float4*)(src + q * 4);
        f[q*4+0] = v.x; f[q*4+1] = v.y; f[q*4+2] = v.z; f[q*4+3] = v.w;
    }
    ushort_t hi[16], lo[16];
#pragma unroll
    for (int e = 0; e < 16; e++) split1(f[e], hi[e], lo[e]);

    ushort_t* dhi = PW + (size_t)(mat * 2 + 0) * PLANE_U;
    ushort_t* dlo = PW + (size_t)(mat * 2 + 1) * PLANE_U;
    const int ks = kc >> 1;
#pragma unroll
    for (int hh = 0; hh < 2; hh++) {
        const int quad = (kc & 1) * 2 + hh;
        const int L    = quad * 16 + jl;
        const size_t base = ((size_t)(nt * 8 + ks)) * 512 + L * 8;
        short8 vh, vl;
#pragma unroll
        for (int e = 0; e < 8; e++) { vh[e] = (short)hi[hh*8+e]; vl[e] = (short)lo[hh*8+e]; }
        *(short8*)(dhi + base) = vh;
        *(short8*)(dlo + base) = vl;
    }
}

// Copy one [32][256] ushort h plane tile into padded LDS [32][264].
__device__ __forceinline__ void stage_plane(const ushort_t* __restrict__ g, ushort_t* s, int tid) {
#pragma unroll
    for (int rnd = 0; rnd < 4; rnd++) {
        int e   = rnd * 2048 + tid * 8;
        int row = e >> 8, k = e & 255;
        short8 v = *(const short8*)(g + e);
        *(short8*)(s + row * 264 + k) = v;
    }
}

// 3 N-tiles x full K=256, 3-pass split-bf16, two M-tiles sharing B regs.
__device__ __forceinline__ void wave_gemm(const ushort_t* sh_hi, const ushort_t* sh_lo,
                                          const ushort_t* __restrict__ bh_base,
                                          const ushort_t* __restrict__ bl_base,
                                          int jbg, int lane, floatx4 acc[3][2]) {
    const int m = lane & 15, quad = lane >> 4;
    const int aoff = m * 264 + quad * 8;
#pragma unroll
    for (int ks = 0; ks < 8; ks++) {
        short8 a0h = *(const short8*)(sh_hi + aoff + ks * 32);
        short8 a0l = *(const short8*)(sh_lo + aoff + ks * 32);
        short8 a1h = *(const short8*)(sh_hi + aoff + 16 * 264 + ks * 32);
        short8 a1l = *(const short8*)(sh_lo + aoff + 16 * 264 + ks * 32);
#pragma unroll
        for (int g = 0; g < 3; g++) {
            const size_t boff = (size_t)(jbg * 3 + g) * 4096 + (size_t)ks * 512 + lane * 8;
            short8 bh = *(const short8*)(bh_base + boff);
            short8 bl = *(const short8*)(bl_base + boff);
            acc[g][0] = __builtin_amdgcn_mfma_f32_16x16x32_bf16(a0h, bh, acc[g][0], 0, 0, 0);
            acc[g][0] = __builtin_amdgcn_mfma_f32_16x16x32_bf16(a0l, bh, acc[g][0], 0, 0, 0);
            acc[g][0] = __builtin_amdgcn_mfma_f32_16x16x32_bf16(a0h, bl, acc[g][0], 0, 0, 0);
            acc[g][1] = __builtin_amdgcn_mfma_f32_16x16x32_bf16(a1h, bh, acc[g][1], 0, 0, 0);
            acc[g][1] = __builtin_amdgcn_mfma_f32_16x16x32_bf16(a1l, bh, acc[g][1], 0, 0, 0);
            acc[g][1] = __builtin_amdgcn_mfma_f32_16x16x32_bf16(a1h, bl, acc[g][1], 0, 0, 0);
        }
    }
}

__global__ __launch_bounds__(256) void gru_step(
    const float* __restrict__ x, int t, int srcp, int dstp,
    const float* __restrict__ Wih0,
    const float* __restrict__ bih0, const float* __restrict__ bhh0,
    const float* __restrict__ bih1, const float* __restrict__ bhh1,
    ushort_t* __restrict__ WS,
    int do_l0, int l0_zero, int do_l1, int l1_zero)
{
    __shared__ ushort_t shA_hi[32 * 264], shA_lo[32 * 264];
    __shared__ ushort_t shB_hi[32 * 264], shB_lo[32 * 264];
    __shared__ float xs[32][10];
    __shared__ float ldH[2][3][32][17];

    const int tid  = threadIdx.x;
    const int lane = tid & 63;
    const int w    = tid >> 6;
    const int jlo  = lane & 15;
    const int quad = lane >> 4;

    if (blockIdx.x < L0B) {
        // ================= layer 0, step t =================
        if (!do_l0) return;
        const int mt = blockIdx.x >> 2, ng = blockIdx.x & 3;
        const int b0 = mt * 32;
        const int jbg = ng * 4 + w;

        for (int u = tid; u < 32 * C_IN; u += 256) {
            int r = u / C_IN, c = u - r * C_IN;
            xs[r][c] = x[(b0 + r) * (C_T * C_IN) + t * C_IN + c];
        }
        const ushort_t* h0hi_s = hplane(WS, 0, srcp);
        const ushort_t* h0lo_s = hplane(WS, 1, srcp);
        if (!l0_zero) {
            stage_plane(h0hi_s + b0 * 256, shA_hi, tid);
            stage_plane(h0lo_s + b0 * 256, shA_lo, tid);
        }
        __syncthreads();

        floatx4 acc[3][2];
#pragma unroll
        for (int g = 0; g < 3; g++) { acc[g][0] = (floatx4){0,0,0,0}; acc[g][1] = (floatx4){0,0,0,0}; }
        if (!l0_zero)
            wave_gemm(shA_hi, shA_lo, WS, WS + PLANE_U, jbg, lane, acc);

        // -------- epilogue (wave-local: tiles g=0,1,2 are r,z,n for jbg) --------
        const int j = jbg * 16 + jlo;
        float wxr[C_IN], wxz[C_IN], wxn[C_IN];
#pragma unroll
        for (int i = 0; i < C_IN; i++) {
            wxr[i] = Wih0[j * C_IN + i];
            wxz[i] = Wih0[(256 + j) * C_IN + i];
            wxn[i] = Wih0[(512 + j) * C_IN + i];
        }
        const float b_r  = bih0[j] + bhh0[j];
        const float b_z  = bih0[256 + j] + bhh0[256 + j];
        const float b_in = bih0[512 + j];
        const float b_hn = bhh0[512 + j];
        ushort_t* h0hi_d = hplane(WS, 0, dstp);
        ushort_t* h0lo_d = hplane(WS, 1, dstp);
#pragma unroll
        for (int m = 0; m < 2; m++) {
#pragma unroll
            for (int r = 0; r < 4; r++) {
                const int row = m * 16 + quad * 4 + r;
                float xr = 0.f, xz = 0.f, xn = 0.f;
#pragma unroll
                for (int i = 0; i < C_IN; i++) {
                    float xv = xs[row][i];
                    xr += xv * wxr[i]; xz += xv * wxz[i]; xn += xv * wxn[i];
                }
                const int gi = (b0 + row) * C_H + j;
                const float hp = l0_zero ? 0.f : load_h(h0hi_s, h0lo_s, gi);
                const float ar = acc[0][m][r] + xr + b_r;
                const float az = acc[1][m][r] + xz + b_z;
                const float inn = xn + b_in;
                const float hn  = acc[2][m][r] + b_hn;
                const float rg = fsig(ar), zg = fsig(az);
                const float nn = ftanh(inn + rg * hn);
                store_h(h0hi_d, h0lo_d, gi, zg * (hp - nn) + nn);
            }
        }
    } else {
        // ================= layer 1, step t-1 =================
        if (!do_l1) return;
        const int bi2 = blockIdx.x - L0B;
        const int mt = bi2 >> 3, ng = bi2 & 7;
        const int b0 = mt * 32;
        const int mat = w >> 1;            // 0: Wih1 over h0_{k-1}, 1: Whh1 over h1_{k-2}
        const int jbsub = w & 1;
        const int jbg = ng * 2 + jbsub;

        const ushort_t* h0hi_s = hplane(WS, 0, srcp);
        const ushort_t* h0lo_s = hplane(WS, 1, srcp);
        const ushort_t* h1hi_s = hplane(WS, 2, srcp);
        const ushort_t* h1lo_s = hplane(WS, 3, srcp);
        stage_plane(h0hi_s + b0 * 256, shA_hi, tid);
        stage_plane(h0lo_s + b0 * 256, shA_lo, tid);
        if (!l1_zero) {
            stage_plane(h1hi_s + b0 * 256, shB_hi, tid);
            stage_plane(h1lo_s + b0 * 256, shB_lo, tid);
        }
        __syncthreads();

        floatx4 acc[3][2];
#pragma unroll
        for (int g = 0; g < 3; g++) { acc[g][0] = (floatx4){0,0,0,0}; acc[g][1] = (floatx4){0,0,0,0}; }
        if (mat == 0)
            wave_gemm(shA_hi, shA_lo, WS + 2 * PLANE_U, WS + 3 * PLANE_U, jbg, lane, acc);
        else if (!l1_zero)
            wave_gemm(shB_hi, shB_lo, WS + 4 * PLANE_U, WS + 5 * PLANE_U, jbg, lane, acc);

        if (mat == 1) {
#pragma unroll
            for (int g = 0; g < 3; g++)
#pragma unroll
                for (int m = 0; m < 2; m++)
#pragma unroll
                    for (int r = 0; r < 4; r++)
                        ldH[jbsub][g][m * 16 + quad * 4 + r][jlo] = acc[g][m][r];
        }
        __syncthreads();

        if (mat == 0) {
            const int j = jbg * 16 + jlo;
            const float b_r  = bih1[j] + bhh1[j];
            const float b_z  = bih1[256 + j] + bhh1[256 + j];
            const float b_in = bih1[512 + j];
            const float b_hn = bhh1[512 + j];
            ushort_t* h1hi_d = hplane(WS, 2, dstp);
            ushort_t* h1lo_d = hplane(WS, 3, dstp);
#pragma unroll
            for (int m = 0; m < 2; m++) {
#pragma unroll
                for (int r = 0; r < 4; r++) {
                    const int row = m * 16 + quad * 4 + r;
                    const int gi = (b0 + row) * C_H + j;
                    const float hp = l1_zero ? 0.f : load_h(h1hi_s, h1lo_s, gi);
                    const float ar = acc[0][m][r] + ldH[jbsub][0][row][jlo] + b_r;
                    const float az = acc[1][m][r] + ldH[jbsub][1][row][jlo] + b_z;
                    const float inn = acc[2][m][r] + b_in;
                    const float hn  = ldH[jbsub][2][row][jlo] + b_hn;
                    const float rg = fsig(ar), zg = fsig(az);
                    const float nn = ftanh(inn + rg * hn);
                    store_h(h1hi_d, h1lo_d, gi, zg * (hp - nn) + nn);
                }
            }
        }
    }
}

__global__ __launch_bounds__(256) void classifier_kernel(
    const ushort_t* __restrict__ WS,
    const float* __restrict__ Wout, const float* __restrict__ bout,
    float* __restrict__ out)
{
    __shared__ float hs[32][C_H + 4];
    __shared__ float lg[32 * C_OUT];
    const int tid = threadIdx.x;
    const int b0  = blockIdx.x * 32;
    const ushort_t* hi_p = WS + US_H + (size_t)(2 * 2 + 1) * HP_SZ;  // h1hi buf 1
    const ushort_t* lo_p = WS + US_H + (size_t)(3 * 2 + 1) * HP_SZ;  // h1lo buf 1
#pragma unroll
    for (int i = 0; i < 32; i++) hs[i][tid] = load_h(hi_p, lo_p, (b0 + i) * C_H + tid);
    __syncthreads();
    for (int u = tid; u < 32 * C_OUT; u += 256) {
        int bb = u / C_OUT, o = u - bb * C_OUT;
        const float* wr = Wout + o * C_H;
        float acc = bout[o];
#pragma unroll 4
        for (int k = 0; k < C_H; k += 4) {
            float4 wv = *(const float4*)(wr + k);
            float4 hv = *(const float4*)(&hs[bb][k]);
            acc += wv.x*hv.x + wv.y*hv.y + wv.z*hv.z + wv.w*hv.w;
        }
        lg[u] = acc;
    }
    __syncthreads();
    if (tid < 32) {
        float mx = -1e30f;
#pragma unroll
        for (int o = 0; o < C_OUT; o++) mx = fmaxf(mx, lg[tid * C_OUT + o]);
        float e[C_OUT];
        float s = 0.0f;
#pragma unroll
        for (int o = 0; o < C_OUT; o++) { e[o] = __expf(lg[tid * C_OUT + o] - mx); s += e[o]; }
        float inv = 1.0f / s;
#pragma unroll
        for (int o = 0; o < C_OUT; o++) out[(b0 + tid) * C_OUT + o] = e[o] * inv;
    }
}

extern "C" void kernel_launch(void* const* d_in, const int* in_sizes, int n_in,
                              void* d_out, int out_size, void* d_ws, size_t ws_size,
                              hipStream_t stream) {
    const float* x    = (const float*)d_in[0];
    // d_in[1] = times (unused), d_in[2] = interpolation_method (unused)
    const float* Wih0 = (const float*)d_in[3];
    const float* Whh0 = (const float*)d_in[4];
    const float* bih0 = (const float*)d_in[5];
    const float* bhh0 = (const float*)d_in[6];
    const float* Wih1 = (const float*)d_in[7];
    const float* Whh1 = (const float*)d_in[8];
    const float* bih1 = (const float*)d_in[9];
    const float* bhh1 = (const float*)d_in[10];
    const float* Wout = (const float*)d_in[11];
    const float* bout = (const float*)d_in[12];
    float* out = (float*)d_out;
    ushort_t* WS = (ushort_t*)d_ws;

    prep_pack<<<144, 256, 0, stream>>>(Whh0, Wih1, Whh1, WS);

    // Launch k: layer0 computes h0_k (src parity (k+1)&1 -> dst k&1);
    //           layer1 computes h1_{k-1} from h0_{k-1} (src) and h1_{k-2} (src).
    for (int k = 0; k <= C_T; k++) {
        int srcp = (k + 1) & 1;
        int dstp = k & 1;
        int do_l0 = (k < C_T) ? 1 : 0;
        int l0z   = (k == 0) ? 1 : 0;
        int do_l1 = (k >= 1) ? 1 : 0;
        int l1z   = (k == 1) ? 1 : 0;
        gru_step<<<NB, 256, 0, stream>>>(x, k, srcp, dstp,
                                         Wih0, bih0, bhh0, bih1, bhh1, WS,
                                         do_l0, l0z, do_l1, l1z);
    }
    // final h1 written at k=365 -> dstp = 1
    classifier_kernel<<<C_B / 32, 256, 0, stream>>>(WS, Wout, bout, out);
}